// Round 1
// baseline (929.073 us; speedup 1.0000x reference)
//
#include <hip/hip_runtime.h>
#include <hip/hip_bf16.h>

// ---- problem constants ----
#define HIDDEN 2048
#define NH 16
#define NKV 8
#define HD 128
#define TN 512      // T_NOISE
#define TC 1536     // T_CTX
#define TNEW 2048   // TC + TN
#define MAXKV 8192

using u16 = unsigned short;
using u32 = unsigned int;

typedef short short8 __attribute__((ext_vector_type(8)));
typedef float floatx4 __attribute__((ext_vector_type(4)));

__device__ __forceinline__ u16 f2bf(float f) {
  u32 u = __float_as_uint(f);
  u += 0x7FFFu + ((u >> 16) & 1u);   // round-to-nearest-even
  return (u16)(u >> 16);
}

__device__ __forceinline__ uint4 pack8(const float* f) {
  uint4 r;
  r.x = (u32)f2bf(f[0]) | ((u32)f2bf(f[1]) << 16);
  r.y = (u32)f2bf(f[2]) | ((u32)f2bf(f[3]) << 16);
  r.z = (u32)f2bf(f[4]) | ((u32)f2bf(f[5]) << 16);
  r.w = (u32)f2bf(f[6]) | ((u32)f2bf(f[7]) << 16);
  return r;
}

__device__ __forceinline__ short8 ldfrag(const u16* p) {
  uint4 v = *(const uint4*)p;
  return __builtin_bit_cast(short8, v);
}

// ============================================================================
// 1) Copy kv caches to output, skipping the [cache_len, cache_len+TNEW) window
// ============================================================================
__global__ __launch_bounds__(256) void cache_copy(
    const float4* __restrict__ inK, const float4* __restrict__ inV,
    float4* __restrict__ outK, float4* __restrict__ outV,
    const int* __restrict__ clp)
{
  const int cl = *clp;
  long long idx = (long long)blockIdx.x * 256 + threadIdx.x;
  const long long per = (long long)NH * MAXKV * (HD / 4);   // 4,194,304
  const float4* src = inK;
  float4* dst = outK;
  long long r = idx;
  if (r >= per) { r -= per; src = inV; dst = outV; }
  int row = (int)((r >> 5) & (MAXKV - 1));  // s index within a head
  if (row >= cl && row < cl + TNEW) return; // will be written by scatter
  dst[r] = src[r];
}

// ============================================================================
// 2) GEMM C(MxN) = A(MxK) @ B(KxN), f32 in/out, bf16 MFMA 16x16x32 inside.
//    A rows come from A0 (first rows0 rows) then A1 (concat support).
//    64x64 block tile, 4 waves (2x2), each wave 32x32 via 2x2 MFMA tiles.
// ============================================================================
__global__ __launch_bounds__(256) void gemm_bf16(
    const float* __restrict__ A0, int rows0, const float* __restrict__ A1,
    const float* __restrict__ B, float* __restrict__ C, int M, int N, int K)
{
  __shared__ u16 As[64 * 40];   // [row][k], stride 40 (pad: conflicts + 16B align)
  __shared__ u16 Bs[64 * 40];   // [n][k] transposed, stride 40
  const int tid = threadIdx.x;
  const int lane = tid & 63;
  const int wave = tid >> 6;
  const int quad = lane >> 4;
  const int m16 = lane & 15;
  const int bm = blockIdx.y * 64;
  const int bn = blockIdx.x * 64;
  const int wm = (wave >> 1) * 32;
  const int wn = (wave & 1) * 32;

  floatx4 acc[2][2];
#pragma unroll
  for (int i = 0; i < 2; i++)
#pragma unroll
    for (int j = 0; j < 2; j++)
#pragma unroll
      for (int r = 0; r < 4; r++) acc[i][j][r] = 0.0f;

  const int arow = tid >> 2, akg = (tid & 3) * 8;  // A stage: 64 rows x 32 k
  const int brow = tid >> 3, bng = (tid & 7) * 8;  // B stage: 32 k x 64 n
  const int garow = bm + arow;
  const float* Ap = (garow < rows0) ? (A0 + (size_t)garow * K)
                                    : (A1 + (size_t)(garow - rows0) * K);

  for (int k0 = 0; k0 < K; k0 += 32) {
    float av[8];
    *(float4*)(av)     = *(const float4*)(Ap + k0 + akg);
    *(float4*)(av + 4) = *(const float4*)(Ap + k0 + akg + 4);
    *(uint4*)&As[arow * 40 + akg] = pack8(av);

    float bv[8];
    const float* Bp = B + (size_t)(k0 + brow) * N + bn + bng;
    *(float4*)(bv)     = *(const float4*)(Bp);
    *(float4*)(bv + 4) = *(const float4*)(Bp + 4);
#pragma unroll
    for (int j = 0; j < 8; j++) Bs[(bng + j) * 40 + brow] = f2bf(bv[j]);

    __syncthreads();

    short8 a0 = ldfrag(&As[(wm + m16) * 40 + quad * 8]);
    short8 a1 = ldfrag(&As[(wm + 16 + m16) * 40 + quad * 8]);
    short8 b0 = ldfrag(&Bs[(wn + m16) * 40 + quad * 8]);
    short8 b1 = ldfrag(&Bs[(wn + 16 + m16) * 40 + quad * 8]);
    acc[0][0] = __builtin_amdgcn_mfma_f32_16x16x32_bf16(a0, b0, acc[0][0], 0, 0, 0);
    acc[0][1] = __builtin_amdgcn_mfma_f32_16x16x32_bf16(a0, b1, acc[0][1], 0, 0, 0);
    acc[1][0] = __builtin_amdgcn_mfma_f32_16x16x32_bf16(a1, b0, acc[1][0], 0, 0, 0);
    acc[1][1] = __builtin_amdgcn_mfma_f32_16x16x32_bf16(a1, b1, acc[1][1], 0, 0, 0);

    __syncthreads();
  }

#pragma unroll
  for (int mt = 0; mt < 2; mt++)
#pragma unroll
    for (int nt = 0; nt < 2; nt++)
#pragma unroll
      for (int r = 0; r < 4; r++) {
        int row = bm + wm + mt * 16 + quad * 4 + r;  // C/D: row = quad*4 + reg
        int col = bn + wn + nt * 16 + m16;           // C/D: col = lane&15
        C[(size_t)row * N + col] = acc[mt][nt][r];
      }
}

// ============================================================================
// 3) Q post: RMSNorm(q_scale) + RoPE + fold sm_scale*log2e, emit bf16
//    one wave per (t, head); lane i handles dims i and i+64 (rope pair)
// ============================================================================
__global__ __launch_bounds__(64) void q_post_k(
    const float* __restrict__ qproj, const int* __restrict__ npos,
    const float* __restrict__ qscale, u16* __restrict__ qbf)
{
  const int t = blockIdx.x, n = blockIdx.y, i = threadIdx.x;
  const size_t base = (size_t)t * HIDDEN + n * HD;
  const float x1 = qproj[base + i];
  const float x2 = qproj[base + i + 64];
  float ss = x1 * x1 + x2 * x2;
#pragma unroll
  for (int m = 1; m < 64; m <<= 1) ss += __shfl_xor(ss, m, 64);
  const float rstd = rsqrtf(ss * (1.0f / HD) + 1e-6f);
  float y1 = x1 * rstd * qscale[i];
  float y2 = x2 * rstd * qscale[i + 64];
  const float pos = (float)npos[t];
  const float ang = pos * exp2f(-(float)i * (19.931568569324174f / 64.0f));
  const float c = cosf(ang), s = sinf(ang);
  const float sc = 0.08838834764831845f * 1.4426950408889634f;  // sm_scale*log2e
  qbf[base + i]      = f2bf((y1 * c - y2 * s) * sc);
  qbf[base + i + 64] = f2bf((y2 * c + y1 * s) * sc);
}

// ============================================================================
// 4) K post: RMSNorm(k_scale) + RoPE, scatter f32 into out cache (GQA repeat)
// ============================================================================
__global__ __launch_bounds__(64) void k_post_k(
    const float* __restrict__ kproj, const int* __restrict__ ctxpos,
    const int* __restrict__ npos, const float* __restrict__ kscale,
    const int* __restrict__ clp, float* __restrict__ outK)
{
  const int t = blockIdx.x, kh = blockIdx.y, i = threadIdx.x;
  const int cl = *clp;
  const size_t base = (size_t)t * (NKV * HD) + kh * HD;
  const float x1 = kproj[base + i];
  const float x2 = kproj[base + i + 64];
  float ss = x1 * x1 + x2 * x2;
#pragma unroll
  for (int m = 1; m < 64; m <<= 1) ss += __shfl_xor(ss, m, 64);
  const float rstd = rsqrtf(ss * (1.0f / HD) + 1e-6f);
  float y1 = x1 * rstd * kscale[i];
  float y2 = x2 * rstd * kscale[i + 64];
  const int posi = (t < TC) ? ctxpos[t] : npos[t - TC];
  const float ang = (float)posi * exp2f(-(float)i * (19.931568569324174f / 64.0f));
  const float c = cosf(ang), s = sinf(ang);
  const float o1 = y1 * c - y2 * s;
  const float o2 = y2 * c + y1 * s;
  const size_t row = (size_t)cl + t;
  const size_t b0 = ((size_t)(2 * kh) * MAXKV + row) * HD;
  const size_t b1 = ((size_t)(2 * kh + 1) * MAXKV + row) * HD;
  outK[b0 + i] = o1; outK[b0 + i + 64] = o2;
  outK[b1 + i] = o1; outK[b1 + i + 64] = o2;
}

// ============================================================================
// 5) V post: scatter v_proj rows into out cache (GQA repeat)
// ============================================================================
__global__ __launch_bounds__(128) void v_post_k(
    const float* __restrict__ vproj, const int* __restrict__ clp,
    float* __restrict__ outV)
{
  const int t = blockIdx.x, kh = blockIdx.y, h = threadIdx.x;
  const int cl = *clp;
  const float v = vproj[(size_t)t * (NKV * HD) + kh * HD + h];
  const size_t row = (size_t)cl + t;
  outV[((size_t)(2 * kh) * MAXKV + row) * HD + h] = v;
  outV[((size_t)(2 * kh + 1) * MAXKV + row) * HD + h] = v;
}

// ============================================================================
// 6) Flash attention, non-causal, valid length = cache_len + TNEW.
//    Grid (TN/64, NH); 4 waves x 16 Q rows; S tiles of 32.
//    Q pre-scaled by sm_scale*log2e -> exp2-based online softmax.
// ============================================================================
__global__ __launch_bounds__(256) void attn_k(
    const u16* __restrict__ qbf, const float* __restrict__ outK,
    const float* __restrict__ outV, const int* __restrict__ clp,
    float* __restrict__ attn)
{
  __shared__ u16 Ks[32 * 136];      // [s][h], stride 136 (pad)
  __shared__ u16 Vt[128 * 40];      // [h][s], stride 40 (pad)
  __shared__ u16 Ps[4 * 16 * 40];   // per-wave P, [t][s], stride 40
  const int tid = threadIdx.x;
  const int lane = tid & 63, wave = tid >> 6;
  const int quad = lane >> 4, m16 = lane & 15;
  const int head = blockIdx.y;
  const int qbase = blockIdx.x * 64 + wave * 16;
  const int Svalid = *clp + TNEW;

  // Q fragments: A[m=lane&15][k=quad*8+j], k blocks of 32 over HD=128
  short8 qf[4];
#pragma unroll
  for (int kb = 0; kb < 4; kb++)
    qf[kb] = ldfrag(&qbf[((size_t)(qbase + m16) * NH + head) * HD + kb * 32 + quad * 8]);

  floatx4 O[8];
#pragma unroll
  for (int i = 0; i < 8; i++)
#pragma unroll
    for (int r = 0; r < 4; r++) O[i][r] = 0.0f;
  float mrow[4], lrow[4];
#pragma unroll
  for (int r = 0; r < 4; r++) { mrow[r] = -1e30f; lrow[r] = 0.0f; }

  const int sstage = tid >> 3;        // 0..31
  const int hg = (tid & 7) * 16;      // 0..112
  const int ntiles = (Svalid + 31) >> 5;

  for (int it = 0; it < ntiles; it++) {
    const int s0 = it * 32;
    {
      int srow = s0 + sstage; if (srow > MAXKV - 1) srow = MAXKV - 1;
      const float* kp = outK + ((size_t)head * MAXKV + srow) * HD + hg;
      float tv[16];
      *(float4*)(tv)      = *(const float4*)(kp);
      *(float4*)(tv + 4)  = *(const float4*)(kp + 4);
      *(float4*)(tv + 8)  = *(const float4*)(kp + 8);
      *(float4*)(tv + 12) = *(const float4*)(kp + 12);
      *(uint4*)&Ks[sstage * 136 + hg]     = pack8(tv);
      *(uint4*)&Ks[sstage * 136 + hg + 8] = pack8(tv + 8);
      const float* vp = outV + ((size_t)head * MAXKV + srow) * HD + hg;
      float vv[16];
      *(float4*)(vv)      = *(const float4*)(vp);
      *(float4*)(vv + 4)  = *(const float4*)(vp + 4);
      *(float4*)(vv + 8)  = *(const float4*)(vp + 8);
      *(float4*)(vv + 12) = *(const float4*)(vp + 12);
#pragma unroll
      for (int j = 0; j < 16; j++) Vt[(hg + j) * 40 + sstage] = f2bf(vv[j]);
    }
    __syncthreads();

    // scores: 16(t) x 32(s) per wave, two 16-col subtiles
    floatx4 sc[2];
#pragma unroll
    for (int st = 0; st < 2; st++) {
      floatx4 a;
#pragma unroll
      for (int r = 0; r < 4; r++) a[r] = 0.0f;
#pragma unroll
      for (int kb = 0; kb < 4; kb++) {
        short8 kf = ldfrag(&Ks[(st * 16 + m16) * 136 + kb * 32 + quad * 8]);
        a = __builtin_amdgcn_mfma_f32_16x16x32_bf16(qf[kb], kf, a, 0, 0, 0);
      }
      const int scol = s0 + st * 16 + m16;
      if (scol >= Svalid) {
#pragma unroll
        for (int r = 0; r < 4; r++) a[r] = -1e30f;
      }
      sc[st] = a;
    }

    // online softmax (rows t = quad*4 + r live in the quad's 16 lanes)
    float alpha[4];
#pragma unroll
    for (int r = 0; r < 4; r++) {
      float mx = fmaxf(sc[0][r], sc[1][r]);
      mx = fmaxf(mx, __shfl_xor(mx, 1, 64));
      mx = fmaxf(mx, __shfl_xor(mx, 2, 64));
      mx = fmaxf(mx, __shfl_xor(mx, 4, 64));
      mx = fmaxf(mx, __shfl_xor(mx, 8, 64));
      const float mn = fmaxf(mrow[r], mx);
      alpha[r] = exp2f(mrow[r] - mn);
      const float p0 = exp2f(sc[0][r] - mn);
      const float p1 = exp2f(sc[1][r] - mn);
      sc[0][r] = p0; sc[1][r] = p1;
      float rs = p0 + p1;
      rs += __shfl_xor(rs, 1, 64);
      rs += __shfl_xor(rs, 2, 64);
      rs += __shfl_xor(rs, 4, 64);
      rs += __shfl_xor(rs, 8, 64);
      lrow[r] = lrow[r] * alpha[r] + rs;
      mrow[r] = mn;
    }
#pragma unroll
    for (int hb = 0; hb < 8; hb++)
#pragma unroll
      for (int r = 0; r < 4; r++) O[hb][r] *= alpha[r];

    // P: C-layout -> LDS -> A-layout (verified m120 pattern)
    u16* myPs = &Ps[wave * 640];
#pragma unroll
    for (int st = 0; st < 2; st++)
#pragma unroll
      for (int r = 0; r < 4; r++)
        myPs[(quad * 4 + r) * 40 + st * 16 + m16] = f2bf(sc[st][r]);
    short8 pf = ldfrag(&myPs[m16 * 40 + quad * 8]);
#pragma unroll
    for (int hb = 0; hb < 8; hb++) {
      short8 vf = ldfrag(&Vt[(hb * 16 + m16) * 40 + quad * 8]);
      O[hb] = __builtin_amdgcn_mfma_f32_16x16x32_bf16(pf, vf, O[hb], 0, 0, 0);
    }
    __syncthreads();
  }

#pragma unroll
  for (int r = 0; r < 4; r++) lrow[r] = 1.0f / lrow[r];
  const int trow = qbase + quad * 4;
#pragma unroll
  for (int hb = 0; hb < 8; hb++)
#pragma unroll
    for (int r = 0; r < 4; r++)
      attn[((size_t)(trow + r) * NH + head) * HD + hb * 16 + m16] = O[hb][r] * lrow[r];
}

// ============================================================================
// launch
// ============================================================================
extern "C" void kernel_launch(void* const* d_in, const int* in_sizes, int n_in,
                              void* d_out, int out_size, void* d_ws, size_t ws_size,
                              hipStream_t stream) {
  const float* x_noise       = (const float*)d_in[0];
  const float* target_hidden = (const float*)d_in[1];
  const int*   noise_pos     = (const int*)d_in[2];
  const int*   ctx_pos       = (const int*)d_in[3];
  const float* inK           = (const float*)d_in[4];
  const float* inV           = (const float*)d_in[5];
  const int*   cache_len     = (const int*)d_in[6];
  const float* wq            = (const float*)d_in[7];
  const float* wk            = (const float*)d_in[8];
  const float* wv            = (const float*)d_in[9];
  const float* wo            = (const float*)d_in[10];
  const float* q_scale       = (const float*)d_in[11];
  const float* k_scale       = (const float*)d_in[12];

  float* out0 = (float*)d_out;
  float* outK = out0 + (size_t)TN * HIDDEN;
  float* outV = outK + (size_t)NH * MAXKV * HD;

  // workspace layout (26 MB total)
  float* qproj = (float*)d_ws;                          // 512x2048
  float* kproj = qproj + (size_t)TN * HIDDEN;           // 2048x1024
  float* vproj = kproj + (size_t)TNEW * NKV * HD;       // 2048x1024
  float* attnb = vproj + (size_t)TNEW * NKV * HD;       // 512x2048
  u16*   qbf   = (u16*)(attnb + (size_t)TN * HIDDEN);   // 512x2048 bf16

  cache_copy<<<dim3(32768), dim3(256), 0, stream>>>(
      (const float4*)inK, (const float4*)inV, (float4*)outK, (float4*)outV, cache_len);

  gemm_bf16<<<dim3(HIDDEN / 64, TN / 64), dim3(256), 0, stream>>>(
      x_noise, TN, x_noise, wq, qproj, TN, HIDDEN, HIDDEN);
  gemm_bf16<<<dim3((NKV * HD) / 64, TNEW / 64), dim3(256), 0, stream>>>(
      target_hidden, TC, x_noise, wk, kproj, TNEW, NKV * HD, HIDDEN);
  gemm_bf16<<<dim3((NKV * HD) / 64, TNEW / 64), dim3(256), 0, stream>>>(
      target_hidden, TC, x_noise, wv, vproj, TNEW, NKV * HD, HIDDEN);

  q_post_k<<<dim3(TN, NH), dim3(64), 0, stream>>>(qproj, noise_pos, q_scale, qbf);
  k_post_k<<<dim3(TNEW, NKV), dim3(64), 0, stream>>>(
      kproj, ctx_pos, noise_pos, k_scale, cache_len, outK);
  v_post_k<<<dim3(TNEW, NKV), dim3(128), 0, stream>>>(vproj, cache_len, outV);

  attn_k<<<dim3(TN / 64, NH), dim3(256), 0, stream>>>(qbf, outK, outV, cache_len, attnb);

  gemm_bf16<<<dim3(HIDDEN / 64, TN / 64), dim3(256), 0, stream>>>(
      attnb, TN, attnb, wo, out0, TN, HIDDEN, HIDDEN);
}

// Round 2
// 555.047 us; speedup vs baseline: 1.6739x; 1.6739x over previous
//
#include <hip/hip_runtime.h>
#include <hip/hip_bf16.h>

// ---- problem constants ----
#define HIDDEN 2048
#define NH 16
#define NKV 8
#define HD 128
#define TN 512      // T_NOISE
#define TC 1536     // T_CTX
#define TNEW 2048   // TC + TN
#define MAXKV 8192

using u16 = unsigned short;
using u32 = unsigned int;

typedef short short8 __attribute__((ext_vector_type(8)));
typedef float floatx4 __attribute__((ext_vector_type(4)));

__device__ __forceinline__ u16 f2bf(float f) {
  u32 u = __float_as_uint(f);
  u += 0x7FFFu + ((u >> 16) & 1u);   // round-to-nearest-even
  return (u16)(u >> 16);
}

__device__ __forceinline__ uint4 pack8(const float* f) {
  uint4 r;
  r.x = (u32)f2bf(f[0]) | ((u32)f2bf(f[1]) << 16);
  r.y = (u32)f2bf(f[2]) | ((u32)f2bf(f[3]) << 16);
  r.z = (u32)f2bf(f[4]) | ((u32)f2bf(f[5]) << 16);
  r.w = (u32)f2bf(f[6]) | ((u32)f2bf(f[7]) << 16);
  return r;
}

__device__ __forceinline__ short8 ldfrag(const u16* p) {
  uint4 v = *(const uint4*)p;
  return __builtin_bit_cast(short8, v);
}

// ============================================================================
// 1) Copy kv caches to output, skipping the [cache_len, cache_len+TNEW) window
// ============================================================================
__global__ __launch_bounds__(256) void cache_copy(
    const float4* __restrict__ inK, const float4* __restrict__ inV,
    float4* __restrict__ outK, float4* __restrict__ outV,
    const int* __restrict__ clp)
{
  const int cl = *clp;
  long long idx = (long long)blockIdx.x * 256 + threadIdx.x;
  const long long per = (long long)NH * MAXKV * (HD / 4);   // 4,194,304
  const float4* src = inK;
  float4* dst = outK;
  long long r = idx;
  if (r >= per) { r -= per; src = inV; dst = outV; }
  int row = (int)((r >> 5) & (MAXKV - 1));  // s index within a head
  if (row >= cl && row < cl + TNEW) return; // will be written by scatter
  dst[r] = src[r];
}

// ============================================================================
// 2) GEMM, f32 in/out, bf16 MFMA 16x16x32. 64x64 tile, 4 waves (2x2).
//    A rows: A0 (first rows0 rows) then A1 (concat support).
//    B/C columns: [0,Nhalf) -> B0/C0, [Nhalf,N) -> B1/C1 (merged-gemm support).
//    Split-K: blockIdx.z selects k-chunk of `ksteps`*32; output offset z*M*Nhalf.
// ============================================================================
__global__ __launch_bounds__(256) void gemm_bf16(
    const float* __restrict__ A0, int rows0, const float* __restrict__ A1,
    const float* __restrict__ B0, const float* __restrict__ B1, int Nhalf,
    float* __restrict__ C0, float* __restrict__ C1,
    int M, int N, int K, int ksteps)
{
  __shared__ u16 As[64 * 40];   // [row][k], stride 40
  __shared__ u16 Bs[64 * 40];   // [n][k] transposed, stride 40
  const int tid = threadIdx.x;
  const int lane = tid & 63;
  const int wave = tid >> 6;
  const int quad = lane >> 4;
  const int m16 = lane & 15;
  const int bm = blockIdx.y * 64;
  const int bn = blockIdx.x * 64;
  const int wm = (wave >> 1) * 32;
  const int wn = (wave & 1) * 32;
  const int z = blockIdx.z;
  const int kbase = z * ksteps * 32;

  const float* B = (bn < Nhalf) ? B0 : B1;
  float*       C = (bn < Nhalf) ? C0 : C1;
  const int n0 = (bn < Nhalf) ? bn : bn - Nhalf;
  const int strideN = (bn < Nhalf) ? Nhalf : (N - Nhalf);

  floatx4 acc[2][2];
#pragma unroll
  for (int i = 0; i < 2; i++)
#pragma unroll
    for (int j = 0; j < 2; j++)
#pragma unroll
      for (int r = 0; r < 4; r++) acc[i][j][r] = 0.0f;

  const int arow = tid >> 2, akg = (tid & 3) * 8;  // A stage: 64 rows x 32 k
  const int brow = tid >> 3, bng = (tid & 7) * 8;  // B stage: 32 k x 64 n
  const int garow = bm + arow;
  const float* Ap = (garow < rows0) ? (A0 + (size_t)garow * K)
                                    : (A1 + (size_t)(garow - rows0) * K);

  for (int ks = 0; ks < ksteps; ks++) {
    const int k0 = kbase + ks * 32;
    if (k0 >= K) break;
    float av[8];
    *(float4*)(av)     = *(const float4*)(Ap + k0 + akg);
    *(float4*)(av + 4) = *(const float4*)(Ap + k0 + akg + 4);
    *(uint4*)&As[arow * 40 + akg] = pack8(av);

    float bv[8];
    const float* Bp = B + (size_t)(k0 + brow) * strideN + n0 + bng;
    *(float4*)(bv)     = *(const float4*)(Bp);
    *(float4*)(bv + 4) = *(const float4*)(Bp + 4);
#pragma unroll
    for (int j = 0; j < 8; j++) Bs[(bng + j) * 40 + brow] = f2bf(bv[j]);

    __syncthreads();

    short8 a0 = ldfrag(&As[(wm + m16) * 40 + quad * 8]);
    short8 a1 = ldfrag(&As[(wm + 16 + m16) * 40 + quad * 8]);
    short8 b0 = ldfrag(&Bs[(wn + m16) * 40 + quad * 8]);
    short8 b1 = ldfrag(&Bs[(wn + 16 + m16) * 40 + quad * 8]);
    acc[0][0] = __builtin_amdgcn_mfma_f32_16x16x32_bf16(a0, b0, acc[0][0], 0, 0, 0);
    acc[0][1] = __builtin_amdgcn_mfma_f32_16x16x32_bf16(a0, b1, acc[0][1], 0, 0, 0);
    acc[1][0] = __builtin_amdgcn_mfma_f32_16x16x32_bf16(a1, b0, acc[1][0], 0, 0, 0);
    acc[1][1] = __builtin_amdgcn_mfma_f32_16x16x32_bf16(a1, b1, acc[1][1], 0, 0, 0);

    __syncthreads();
  }

  const size_t zoff = (size_t)z * M * Nhalf;
#pragma unroll
  for (int mt = 0; mt < 2; mt++)
#pragma unroll
    for (int nt = 0; nt < 2; nt++)
#pragma unroll
      for (int r = 0; r < 4; r++) {
        int row = bm + wm + mt * 16 + quad * 4 + r;  // C/D: row = quad*4 + reg
        int col = wn + nt * 16 + m16;                // within 64-tile
        C[zoff + (size_t)row * strideN + n0 + col] = acc[mt][nt][r];
      }
}

// ============================================================================
// 2b) reduce 4 split-K partials: C = sum_z P[z]
// ============================================================================
__global__ __launch_bounds__(256) void reduce4(
    const float4* __restrict__ P, float4* __restrict__ C, int n4)
{
  int idx = blockIdx.x * 256 + threadIdx.x;
  if (idx >= n4) return;
  float4 a = P[idx], b = P[idx + n4], c = P[idx + 2 * n4], d = P[idx + 3 * n4];
  float4 r;
  r.x = (a.x + b.x) + (c.x + d.x);
  r.y = (a.y + b.y) + (c.y + d.y);
  r.z = (a.z + b.z) + (c.z + d.z);
  r.w = (a.w + b.w) + (c.w + d.w);
  C[idx] = r;
}

// ============================================================================
// 3) Q post: RMSNorm(q_scale) + RoPE + fold sm_scale*log2e, emit bf16
// ============================================================================
__global__ __launch_bounds__(64) void q_post_k(
    const float* __restrict__ qproj, const int* __restrict__ npos,
    const float* __restrict__ qscale, u16* __restrict__ qbf)
{
  const int t = blockIdx.x, n = blockIdx.y, i = threadIdx.x;
  const size_t base = (size_t)t * HIDDEN + n * HD;
  const float x1 = qproj[base + i];
  const float x2 = qproj[base + i + 64];
  float ss = x1 * x1 + x2 * x2;
#pragma unroll
  for (int m = 1; m < 64; m <<= 1) ss += __shfl_xor(ss, m, 64);
  const float rstd = rsqrtf(ss * (1.0f / HD) + 1e-6f);
  float y1 = x1 * rstd * qscale[i];
  float y2 = x2 * rstd * qscale[i + 64];
  const float pos = (float)npos[t];
  const float ang = pos * exp2f(-(float)i * (19.931568569324174f / 64.0f));
  const float c = cosf(ang), s = sinf(ang);
  const float sc = 0.08838834764831845f * 1.4426950408889634f;  // sm_scale*log2e
  qbf[base + i]      = f2bf((y1 * c - y2 * s) * sc);
  qbf[base + i + 64] = f2bf((y2 * c + y1 * s) * sc);
}

// ============================================================================
// 4) K post: RMSNorm(k_scale) + RoPE, scatter f32 into out cache (GQA repeat)
// ============================================================================
__global__ __launch_bounds__(64) void k_post_k(
    const float* __restrict__ kproj, const int* __restrict__ ctxpos,
    const int* __restrict__ npos, const float* __restrict__ kscale,
    const int* __restrict__ clp, float* __restrict__ outK)
{
  const int t = blockIdx.x, kh = blockIdx.y, i = threadIdx.x;
  const int cl = *clp;
  const size_t base = (size_t)t * (NKV * HD) + kh * HD;
  const float x1 = kproj[base + i];
  const float x2 = kproj[base + i + 64];
  float ss = x1 * x1 + x2 * x2;
#pragma unroll
  for (int m = 1; m < 64; m <<= 1) ss += __shfl_xor(ss, m, 64);
  const float rstd = rsqrtf(ss * (1.0f / HD) + 1e-6f);
  float y1 = x1 * rstd * kscale[i];
  float y2 = x2 * rstd * kscale[i + 64];
  const int posi = (t < TC) ? ctxpos[t] : npos[t - TC];
  const float ang = (float)posi * exp2f(-(float)i * (19.931568569324174f / 64.0f));
  const float c = cosf(ang), s = sinf(ang);
  const float o1 = y1 * c - y2 * s;
  const float o2 = y2 * c + y1 * s;
  const size_t row = (size_t)cl + t;
  const size_t b0 = ((size_t)(2 * kh) * MAXKV + row) * HD;
  const size_t b1 = ((size_t)(2 * kh + 1) * MAXKV + row) * HD;
  outK[b0 + i] = o1; outK[b0 + i + 64] = o2;
  outK[b1 + i] = o1; outK[b1 + i + 64] = o2;
}

// ============================================================================
// 5) V post: scatter v_proj rows into out cache (GQA repeat)
// ============================================================================
__global__ __launch_bounds__(128) void v_post_k(
    const float* __restrict__ vproj, const int* __restrict__ clp,
    float* __restrict__ outV)
{
  const int t = blockIdx.x, kh = blockIdx.y, h = threadIdx.x;
  const int cl = *clp;
  const float v = vproj[(size_t)t * (NKV * HD) + kh * HD + h];
  const size_t row = (size_t)cl + t;
  outV[((size_t)(2 * kh) * MAXKV + row) * HD + h] = v;
  outV[((size_t)(2 * kh + 1) * MAXKV + row) * HD + h] = v;
}

// ============================================================================
// 6) Flash attention (split-S). Grid (TN/64, NH, splits); 4 waves x 16 Q rows.
//    Writes unnormalized partial O + per-row (m, l) for each split.
// ============================================================================
__global__ __launch_bounds__(256) void attn_k(
    const u16* __restrict__ qbf, const float* __restrict__ outK,
    const float* __restrict__ outV, const int* __restrict__ clp,
    float* __restrict__ Opart, float* __restrict__ Oml)
{
  __shared__ u16 Ks[32 * 136];      // [s][h], stride 136
  __shared__ u16 Vt[128 * 40];      // [h][s], stride 40
  __shared__ u16 Ps[4 * 16 * 40];   // per-wave P, [t][s], stride 40
  const int tid = threadIdx.x;
  const int lane = tid & 63, wave = tid >> 6;
  const int quad = lane >> 4, m16 = lane & 15;
  const int head = blockIdx.y;
  const int qbase = blockIdx.x * 64 + wave * 16;
  const int z = blockIdx.z, splits = gridDim.z;
  const int Svalid = *clp + TNEW;
  const int ntiles = (Svalid + 31) >> 5;
  const int per = (ntiles + splits - 1) / splits;
  const int it0 = z * per;
  const int it1 = min(ntiles, it0 + per);

  short8 qf[4];
#pragma unroll
  for (int kb = 0; kb < 4; kb++)
    qf[kb] = ldfrag(&qbf[((size_t)(qbase + m16) * NH + head) * HD + kb * 32 + quad * 8]);

  floatx4 O[8];
#pragma unroll
  for (int i = 0; i < 8; i++)
#pragma unroll
    for (int r = 0; r < 4; r++) O[i][r] = 0.0f;
  float mrow[4], lrow[4];
#pragma unroll
  for (int r = 0; r < 4; r++) { mrow[r] = -1e30f; lrow[r] = 0.0f; }

  const int sstage = tid >> 3;        // 0..31
  const int hg = (tid & 7) * 16;      // 0..112

  for (int it = it0; it < it1; it++) {
    const int s0 = it * 32;
    {
      int srow = s0 + sstage; if (srow > MAXKV - 1) srow = MAXKV - 1;
      const float* kp = outK + ((size_t)head * MAXKV + srow) * HD + hg;
      float tv[16];
      *(float4*)(tv)      = *(const float4*)(kp);
      *(float4*)(tv + 4)  = *(const float4*)(kp + 4);
      *(float4*)(tv + 8)  = *(const float4*)(kp + 8);
      *(float4*)(tv + 12) = *(const float4*)(kp + 12);
      *(uint4*)&Ks[sstage * 136 + hg]     = pack8(tv);
      *(uint4*)&Ks[sstage * 136 + hg + 8] = pack8(tv + 8);
      const float* vp = outV + ((size_t)head * MAXKV + srow) * HD + hg;
      float vv[16];
      *(float4*)(vv)      = *(const float4*)(vp);
      *(float4*)(vv + 4)  = *(const float4*)(vp + 4);
      *(float4*)(vv + 8)  = *(const float4*)(vp + 8);
      *(float4*)(vv + 12) = *(const float4*)(vp + 12);
#pragma unroll
      for (int j = 0; j < 16; j++) Vt[(hg + j) * 40 + sstage] = f2bf(vv[j]);
    }
    __syncthreads();

    floatx4 sc[2];
#pragma unroll
    for (int st = 0; st < 2; st++) {
      floatx4 a;
#pragma unroll
      for (int r = 0; r < 4; r++) a[r] = 0.0f;
#pragma unroll
      for (int kb = 0; kb < 4; kb++) {
        short8 kf = ldfrag(&Ks[(st * 16 + m16) * 136 + kb * 32 + quad * 8]);
        a = __builtin_amdgcn_mfma_f32_16x16x32_bf16(qf[kb], kf, a, 0, 0, 0);
      }
      const int scol = s0 + st * 16 + m16;
      if (scol >= Svalid) {
#pragma unroll
        for (int r = 0; r < 4; r++) a[r] = -1e30f;
      }
      sc[st] = a;
    }

    float alpha[4];
#pragma unroll
    for (int r = 0; r < 4; r++) {
      float mx = fmaxf(sc[0][r], sc[1][r]);
      mx = fmaxf(mx, __shfl_xor(mx, 1, 64));
      mx = fmaxf(mx, __shfl_xor(mx, 2, 64));
      mx = fmaxf(mx, __shfl_xor(mx, 4, 64));
      mx = fmaxf(mx, __shfl_xor(mx, 8, 64));
      const float mn = fmaxf(mrow[r], mx);
      alpha[r] = exp2f(mrow[r] - mn);
      const float p0 = exp2f(sc[0][r] - mn);
      const float p1 = exp2f(sc[1][r] - mn);
      sc[0][r] = p0; sc[1][r] = p1;
      float rs = p0 + p1;
      rs += __shfl_xor(rs, 1, 64);
      rs += __shfl_xor(rs, 2, 64);
      rs += __shfl_xor(rs, 4, 64);
      rs += __shfl_xor(rs, 8, 64);
      lrow[r] = lrow[r] * alpha[r] + rs;
      mrow[r] = mn;
    }
#pragma unroll
    for (int hb = 0; hb < 8; hb++)
#pragma unroll
      for (int r = 0; r < 4; r++) O[hb][r] *= alpha[r];

    u16* myPs = &Ps[wave * 640];
#pragma unroll
    for (int st = 0; st < 2; st++)
#pragma unroll
      for (int r = 0; r < 4; r++)
        myPs[(quad * 4 + r) * 40 + st * 16 + m16] = f2bf(sc[st][r]);
    short8 pf = ldfrag(&myPs[m16 * 40 + quad * 8]);
#pragma unroll
    for (int hb = 0; hb < 8; hb++) {
      short8 vf = ldfrag(&Vt[(hb * 16 + m16) * 40 + quad * 8]);
      O[hb] = __builtin_amdgcn_mfma_f32_16x16x32_bf16(pf, vf, O[hb], 0, 0, 0);
    }
    __syncthreads();
  }

  // write unnormalized partials + (m,l)
  const size_t zbase = (size_t)z * TN * NH;
  const int trow = qbase + quad * 4;
#pragma unroll
  for (int hb = 0; hb < 8; hb++)
#pragma unroll
    for (int r = 0; r < 4; r++)
      Opart[(zbase + (size_t)(trow + r) * NH + head) * HD + hb * 16 + m16] = O[hb][r];
  if (m16 == 0) {
#pragma unroll
    for (int r = 0; r < 4; r++) {
      Oml[(zbase + (size_t)(trow + r) * NH + head) * 2 + 0] = mrow[r];
      Oml[(zbase + (size_t)(trow + r) * NH + head) * 2 + 1] = lrow[r];
    }
  }
}

// ============================================================================
// 6b) combine split-S partials -> attnb [t][head][hd]
// ============================================================================
__global__ __launch_bounds__(128) void attn_combine(
    const float* __restrict__ Opart, const float* __restrict__ Oml,
    float* __restrict__ attnb, int splits)
{
  const int pair = blockIdx.x;   // t*NH + head
  const int h = threadIdx.x;
  float M = -1e30f;
  for (int zz = 0; zz < splits; zz++)
    M = fmaxf(M, Oml[((size_t)zz * TN * NH + pair) * 2]);
  float l = 0.0f, o = 0.0f;
  for (int zz = 0; zz < splits; zz++) {
    const float mi = Oml[((size_t)zz * TN * NH + pair) * 2];
    const float li = Oml[((size_t)zz * TN * NH + pair) * 2 + 1];
    const float w = exp2f(mi - M);
    l += li * w;
    o += Opart[((size_t)zz * TN * NH + pair) * HD + h] * w;
  }
  attnb[(size_t)pair * HD + h] = o / l;
}

// ============================================================================
// launch
// ============================================================================
extern "C" void kernel_launch(void* const* d_in, const int* in_sizes, int n_in,
                              void* d_out, int out_size, void* d_ws, size_t ws_size,
                              hipStream_t stream) {
  const float* x_noise       = (const float*)d_in[0];
  const float* target_hidden = (const float*)d_in[1];
  const int*   noise_pos     = (const int*)d_in[2];
  const int*   ctx_pos       = (const int*)d_in[3];
  const float* inK           = (const float*)d_in[4];
  const float* inV           = (const float*)d_in[5];
  const int*   cache_len     = (const int*)d_in[6];
  const float* wq            = (const float*)d_in[7];
  const float* wk            = (const float*)d_in[8];
  const float* wv            = (const float*)d_in[9];
  const float* wo            = (const float*)d_in[10];
  const float* q_scale       = (const float*)d_in[11];
  const float* k_scale       = (const float*)d_in[12];

  float* out0 = (float*)d_out;
  float* outK = out0 + (size_t)TN * HIDDEN;
  float* outV = outK + (size_t)NH * MAXKV * HD;

  // ---- workspace layout ----
  size_t off = 0;
  auto walloc = [&](size_t bytes) -> void* {
    void* p = (char*)d_ws + off;
    off += (bytes + 255) & ~(size_t)255;
    return p;
  };
  u16*   qbf   = (u16*)walloc((size_t)TN * HIDDEN * 2);
  float* attnb = (float*)walloc((size_t)TN * HIDDEN * 4);
  float* qproj = (float*)walloc((size_t)TN * HIDDEN * 4);
  float* kproj = (float*)walloc((size_t)TNEW * NKV * HD * 4);
  float* vproj = (float*)walloc((size_t)TNEW * NKV * HD * 4);
  float* scratch = (float*)((char*)d_ws + off);
  const size_t avail = (ws_size > off) ? (ws_size - off) : 0;

  // attention split count sized to scratch
  const size_t per_split = (size_t)TN * NH * HD * 4 + (size_t)TN * NH * 8;
  int asplits = 2;
  if (avail >= 8 * per_split) asplits = 8;
  else if (avail >= 4 * per_split) asplits = 4;
  float* Opart = scratch;
  float* Oml   = Opart + (size_t)asplits * TN * NH * HD;

  // gemm split-K partials (16 MB) share scratch (phases don't overlap in time)
  const bool ksplit = (avail >= (size_t)4 * TN * HIDDEN * 4);
  float* gpart = scratch;

  cache_copy<<<dim3(32768), dim3(256), 0, stream>>>(
      (const float4*)inK, (const float4*)inV, (float4*)outK, (float4*)outV, cache_len);

  // Q projection: split-K x4
  if (ksplit) {
    gemm_bf16<<<dim3(HIDDEN / 64, TN / 64, 4), dim3(256), 0, stream>>>(
        x_noise, TN, x_noise, wq, wq, HIDDEN, gpart, gpart, TN, HIDDEN, HIDDEN, 16);
    reduce4<<<dim3((TN * HIDDEN / 4 + 255) / 256), dim3(256), 0, stream>>>(
        (const float4*)gpart, (float4*)qproj, TN * HIDDEN / 4);
  } else {
    gemm_bf16<<<dim3(HIDDEN / 64, TN / 64, 1), dim3(256), 0, stream>>>(
        x_noise, TN, x_noise, wq, wq, HIDDEN, qproj, qproj, TN, HIDDEN, HIDDEN, 64);
  }

  // merged K+V projection (N = 2048 -> 32x32 grid)
  gemm_bf16<<<dim3(2 * NKV * HD / 64, TNEW / 64, 1), dim3(256), 0, stream>>>(
      target_hidden, TC, x_noise, wk, wv, NKV * HD, kproj, vproj,
      TNEW, 2 * NKV * HD, HIDDEN, 64);

  q_post_k<<<dim3(TN, NH), dim3(64), 0, stream>>>(qproj, noise_pos, q_scale, qbf);
  k_post_k<<<dim3(TNEW, NKV), dim3(64), 0, stream>>>(
      kproj, ctx_pos, noise_pos, k_scale, cache_len, outK);
  v_post_k<<<dim3(TNEW, NKV), dim3(128), 0, stream>>>(vproj, cache_len, outV);

  attn_k<<<dim3(TN / 64, NH, asplits), dim3(256), 0, stream>>>(
      qbf, outK, outV, cache_len, Opart, Oml);
  attn_combine<<<dim3(TN * NH), dim3(128), 0, stream>>>(Opart, Oml, attnb, asplits);

  // output projection: split-K x4
  if (ksplit) {
    gemm_bf16<<<dim3(HIDDEN / 64, TN / 64, 4), dim3(256), 0, stream>>>(
        attnb, TN, attnb, wo, wo, HIDDEN, gpart, gpart, TN, HIDDEN, HIDDEN, 16);
    reduce4<<<dim3((TN * HIDDEN / 4 + 255) / 256), dim3(256), 0, stream>>>(
        (const float4*)gpart, (float4*)out0, TN * HIDDEN / 4);
  } else {
    gemm_bf16<<<dim3(HIDDEN / 64, TN / 64, 1), dim3(256), 0, stream>>>(
        attnb, TN, attnb, wo, wo, HIDDEN, out0, out0, TN, HIDDEN, HIDDEN, 64);
  }
}